// Round 1
// baseline (370.895 us; speedup 1.0000x reference)
//
#include <hip/hip_runtime.h>

// QNet forward, fp32, MI355X.
// B=65536 rows, obs=1129 cols (37 self + 39*28 others).
// Block: 256 threads, 128 rows. Grid: B/128 = 512 (exactly 2 blocks/CU).
//
// Thread mapping (both passes): rs = t&63 owns rows {2rs, 2rs+1};
// cg = t>>6 owns a column group (10 logit cols in pass 1, 8 enc dims in pass 2).
// Weight operands are wave-uniform -> readfirstlane + scalar loads (SMEM path),
// keeping the LDS pipe for the per-row A operand only (float2, transposed+padded).

constexpr int TM      = 128;   // rows per block
constexpr int KC      = 64;    // k-chunk, pass 1
constexpr int NCH1    = 18;    // ceil(1129/64)
constexpr int OBS     = 1129;
constexpr int SA_STR  = 132;   // pass-1 sA stride (even: float2-aligned; 132%32=4)
constexpr int SA2_STR = 130;   // pass-2 sA stride
constexpr int NLOG    = 41;    // padded logit row

__global__ __launch_bounds__(256, 2)
void qnet_fwd(const float* __restrict__ obs,
              const float* __restrict__ W_al,   const float* __restrict__ b_al,
              const float* __restrict__ W_self, const float* __restrict__ b_self,
              const float* __restrict__ W_oth,  const float* __restrict__ b_oth,
              const float* __restrict__ W_ao,   const float* __restrict__ b_ao,
              const float* __restrict__ W_emb,  const float* __restrict__ b_emb,
              const float* __restrict__ W_out,  const float* __restrict__ b_out,
              float* __restrict__ out)
{
    __shared__ float sA[8448];          // pass1 A-tile / pass2 A-tile / sAtt+sH1
    __shared__ float sLg[TM * NLOG];    // logits -> att_w -> sH2

    const int t    = threadIdx.x;
    const int row0 = blockIdx.x * TM;
    const int rs   = t & 63;
    const int cg   = t >> 6;

    // ================= pass 1: logits = obs @ W_al + b_al =================
    const int j0s = __builtin_amdgcn_readfirstlane(cg * 10);

    float acc[2][10];
#pragma unroll
    for (int u = 0; u < 2; ++u)
#pragma unroll
        for (int j = 0; j < 10; ++j) acc[u][j] = 0.f;

    for (int kc = 0; kc < NCH1; ++kc) {
        const int k0 = kc * KC;
        __syncthreads();
        // stage transposed: sA[c*SA_STR + r] = obs[row0+r][k0+c]  (zero-pad tail)
#pragma unroll
        for (int i = 0; i < 32; ++i) {
            int p = i * 256 + t;          // 128 rows x 64 cols
            int r = p >> 6;
            int c = p & 63;
            int gk = k0 + c;
            float v = (gk < OBS) ? obs[(row0 + r) * OBS + gk] : 0.f;
            sA[c * SA_STR + r] = v;
        }
        __syncthreads();
#pragma unroll 4
        for (int k = 0; k < KC; ++k) {
            int kk = k0 + k;
            kk = (kk < OBS) ? kk : (OBS - 1);          // clamp: A is zero there
            const float* w = W_al + kk * 40 + j0s;     // uniform -> scalar loads
            float2 a = *(const float2*)(sA + k * SA_STR + 2 * rs);
#pragma unroll
            for (int j = 0; j < 10; ++j) {
                float wv = w[j];
                acc[0][j] = fmaf(a.x, wv, acc[0][j]);
                acc[1][j] = fmaf(a.y, wv, acc[1][j]);
            }
        }
    }
    // logits -> LDS (+bias)
#pragma unroll
    for (int u = 0; u < 2; ++u)
#pragma unroll
        for (int j = 0; j < 10; ++j)
            sLg[(2 * rs + u) * NLOG + j0s + j] = acc[u][j] + b_al[j0s + j];
    __syncthreads();

    // softmax per row, in place (threads 0..127, one row each)
    if (t < TM) {
        float* Lr = sLg + t * NLOG;
        float m = -3.4e38f;
        for (int j = 0; j < 40; ++j) m = fmaxf(m, Lr[j]);
        float s = 0.f;
        for (int j = 0; j < 40; ++j) s += __expf(Lr[j] - m);
        float inv = 1.0f / s;
        for (int j = 0; j < 40; ++j) Lr[j] = __expf(Lr[j] - m) * inv;
    }
    __syncthreads();

    // ================= pass 2: encodings + weighted sum =================
    const int e0s = __builtin_amdgcn_readfirstlane(cg * 8);

    float att[2][8];

    // ---- self encoding (no relu), att_w[0] ----
#pragma unroll
    for (int i = 0; i < 20; ++i) {
        int p = i * 256 + t;              // 128 rows x 40 cols (use 0..36)
        int r = p / 40;
        int c = p - r * 40;
        sA[c * SA2_STR + r] = obs[(row0 + r) * OBS + c];
    }
    __syncthreads();
    {
        float se[2][8];
#pragma unroll
        for (int u = 0; u < 2; ++u)
#pragma unroll
            for (int j = 0; j < 8; ++j) se[u][j] = b_self[e0s + j];
#pragma unroll 4
        for (int k = 0; k < 37; ++k) {
            const float* w = W_self + k * 32 + e0s;
            float2 a = *(const float2*)(sA + k * SA2_STR + 2 * rs);
#pragma unroll
            for (int j = 0; j < 8; ++j) {
                float wv = w[j];
                se[0][j] = fmaf(a.x, wv, se[0][j]);
                se[1][j] = fmaf(a.y, wv, se[1][j]);
            }
        }
        float w0a = sLg[(2 * rs) * NLOG];
        float w0b = sLg[(2 * rs + 1) * NLOG];
#pragma unroll
        for (int j = 0; j < 8; ++j) {
            att[0][j] = w0a * se[0][j];
            att[1][j] = w0b * se[1][j];
        }
    }

    // ---- other agents: relu(obs_chunk @ W_oth + b), 2 agents per chunk ----
    for (int ch = 0; ch < 20; ++ch) {
        const int col0 = 37 + ch * 56;
        const bool two = (ch < 19);
        __syncthreads();
        if (two) {
#pragma unroll
            for (int i = 0; i < 28; ++i) {
                int p = i * 256 + t;      // 128 x 56
                int r = p / 56;
                int c = p - r * 56;
                sA[c * SA2_STR + r] = obs[(row0 + r) * OBS + col0 + c];
            }
        } else {
#pragma unroll
            for (int i = 0; i < 14; ++i) {
                int p = i * 256 + t;      // 128 x 28
                int r = p / 28;
                int c = p - r * 28;
                sA[c * SA2_STR + r] = obs[(row0 + r) * OBS + col0 + c];
            }
        }
        __syncthreads();
        if (two) {
            float se[2][2][8];            // [agent][row][dim]
#pragma unroll
            for (int a = 0; a < 2; ++a)
#pragma unroll
                for (int u = 0; u < 2; ++u)
#pragma unroll
                    for (int j = 0; j < 8; ++j) se[a][u][j] = b_oth[e0s + j];
#pragma unroll 2
            for (int k = 0; k < 28; ++k) {
                const float* w = W_oth + k * 32 + e0s;
                float2 a0 = *(const float2*)(sA + k * SA2_STR + 2 * rs);
                float2 a1 = *(const float2*)(sA + (28 + k) * SA2_STR + 2 * rs);
#pragma unroll
                for (int j = 0; j < 8; ++j) {
                    float wv = w[j];
                    se[0][0][j] = fmaf(a0.x, wv, se[0][0][j]);
                    se[0][1][j] = fmaf(a0.y, wv, se[0][1][j]);
                    se[1][0][j] = fmaf(a1.x, wv, se[1][0][j]);
                    se[1][1][j] = fmaf(a1.y, wv, se[1][1][j]);
                }
            }
            const int n = ch * 2;
            float wA0 = sLg[(2 * rs) * NLOG + 1 + n];
            float wB0 = sLg[(2 * rs + 1) * NLOG + 1 + n];
            float wA1 = sLg[(2 * rs) * NLOG + 2 + n];
            float wB1 = sLg[(2 * rs + 1) * NLOG + 2 + n];
#pragma unroll
            for (int j = 0; j < 8; ++j) {
                att[0][j] += wA0 * fmaxf(se[0][0][j], 0.f) + wA1 * fmaxf(se[1][0][j], 0.f);
                att[1][j] += wB0 * fmaxf(se[0][1][j], 0.f) + wB1 * fmaxf(se[1][1][j], 0.f);
            }
        } else {
            float se[2][8];
#pragma unroll
            for (int u = 0; u < 2; ++u)
#pragma unroll
                for (int j = 0; j < 8; ++j) se[u][j] = b_oth[e0s + j];
#pragma unroll 2
            for (int k = 0; k < 28; ++k) {
                const float* w = W_oth + k * 32 + e0s;
                float2 a0 = *(const float2*)(sA + k * SA2_STR + 2 * rs);
#pragma unroll
                for (int j = 0; j < 8; ++j) {
                    float wv = w[j];
                    se[0][j] = fmaf(a0.x, wv, se[0][j]);
                    se[1][j] = fmaf(a0.y, wv, se[1][j]);
                }
            }
            const int n = ch * 2;
            float wA0 = sLg[(2 * rs) * NLOG + 1 + n];
            float wB0 = sLg[(2 * rs + 1) * NLOG + 1 + n];
#pragma unroll
            for (int j = 0; j < 8; ++j) {
                att[0][j] += wA0 * fmaxf(se[0][j], 0.f);
                att[1][j] += wB0 * fmaxf(se[1][j], 0.f);
            }
        }
    }

    // ================= head: 3 small dense layers =================
    __syncthreads();
    // att_out -> sAtt (sA[0:4224)), stride 33
#pragma unroll
    for (int u = 0; u < 2; ++u)
#pragma unroll
        for (int j = 0; j < 8; ++j)
            sA[(2 * rs + u) * 33 + e0s + j] = att[u][j];
    __syncthreads();

    // h1 = relu(att_out @ W_ao + b_ao) -> sA[4224 + ...]
    {
        float h[2][8];
#pragma unroll
        for (int u = 0; u < 2; ++u)
#pragma unroll
            for (int j = 0; j < 8; ++j) h[u][j] = b_ao[e0s + j];
#pragma unroll 4
        for (int k = 0; k < 32; ++k) {
            const float* w = W_ao + k * 32 + e0s;
            float x0 = sA[(2 * rs) * 33 + k];
            float x1 = sA[(2 * rs + 1) * 33 + k];
#pragma unroll
            for (int j = 0; j < 8; ++j) {
                float wv = w[j];
                h[0][j] = fmaf(x0, wv, h[0][j]);
                h[1][j] = fmaf(x1, wv, h[1][j]);
            }
        }
        __syncthreads();
#pragma unroll
        for (int u = 0; u < 2; ++u)
#pragma unroll
            for (int j = 0; j < 8; ++j)
                sA[4224 + (2 * rs + u) * 33 + e0s + j] = fmaxf(h[u][j], 0.f);
    }
    __syncthreads();

    // h2 = relu(h1 @ W_emb + b_emb) -> sLg (att_w dead)
    {
        float h[2][8];
#pragma unroll
        for (int u = 0; u < 2; ++u)
#pragma unroll
            for (int j = 0; j < 8; ++j) h[u][j] = b_emb[e0s + j];
#pragma unroll 4
        for (int k = 0; k < 32; ++k) {
            const float* w = W_emb + k * 32 + e0s;
            float x0 = sA[4224 + (2 * rs) * 33 + k];
            float x1 = sA[4224 + (2 * rs + 1) * 33 + k];
#pragma unroll
            for (int j = 0; j < 8; ++j) {
                float wv = w[j];
                h[0][j] = fmaf(x0, wv, h[0][j]);
                h[1][j] = fmaf(x1, wv, h[1][j]);
            }
        }
        __syncthreads();
#pragma unroll
        for (int u = 0; u < 2; ++u)
#pragma unroll
            for (int j = 0; j < 8; ++j)
                sLg[(2 * rs + u) * 33 + e0s + j] = fmaxf(h[u][j], 0.f);
    }
    __syncthreads();

    // out = h2 @ W_out + b_out  (21 cols: cg 0,1 -> 8 each, cg 2 -> 5)
    if (cg < 3) {
        const int o0s = __builtin_amdgcn_readfirstlane(cg * 8);
        float o[2][8];
#pragma unroll
        for (int u = 0; u < 2; ++u)
#pragma unroll
            for (int j = 0; j < 8; ++j)
                o[u][j] = (o0s + j < 21) ? b_out[o0s + j] : 0.f;
#pragma unroll 4
        for (int k = 0; k < 32; ++k) {
            const float* w = W_out + k * 21 + o0s;
            float x0 = sLg[(2 * rs) * 33 + k];
            float x1 = sLg[(2 * rs + 1) * 33 + k];
#pragma unroll
            for (int j = 0; j < 8; ++j) {
                if (o0s + j < 21) {
                    float wv = w[j];
                    o[0][j] = fmaf(x0, wv, o[0][j]);
                    o[1][j] = fmaf(x1, wv, o[1][j]);
                }
            }
        }
#pragma unroll
        for (int u = 0; u < 2; ++u)
#pragma unroll
            for (int j = 0; j < 8; ++j)
                if (o0s + j < 21)
                    out[(row0 + 2 * rs + u) * 21 + o0s + j] = o[u][j];
    }
}

extern "C" void kernel_launch(void* const* d_in, const int* in_sizes, int n_in,
                              void* d_out, int out_size, void* d_ws, size_t ws_size,
                              hipStream_t stream) {
    const float* obs    = (const float*)d_in[0];
    const float* W_al   = (const float*)d_in[1];
    const float* b_al   = (const float*)d_in[2];
    const float* W_self = (const float*)d_in[3];
    const float* b_self = (const float*)d_in[4];
    const float* W_oth  = (const float*)d_in[5];
    const float* b_oth  = (const float*)d_in[6];
    const float* W_ao   = (const float*)d_in[7];
    const float* b_ao   = (const float*)d_in[8];
    const float* W_emb  = (const float*)d_in[9];
    const float* b_emb  = (const float*)d_in[10];
    const float* W_out  = (const float*)d_in[11];
    const float* b_out  = (const float*)d_in[12];
    float* out = (float*)d_out;

    const int B = in_sizes[0] / 1129;       // 65536
    const int grid = B / 128;               // 512
    qnet_fwd<<<grid, 256, 0, stream>>>(obs, W_al, b_al, W_self, b_self,
                                       W_oth, b_oth, W_ao, b_ao,
                                       W_emb, b_emb, W_out, b_out, out);
}

// Round 2
// 331.575 us; speedup vs baseline: 1.1186x; 1.1186x over previous
//
#include <hip/hip_runtime.h>

// QNet forward, fp32, MI355X — register-streaming version.
// B=65536 rows, obs=1129 cols (37 self + 39*28 others).
//
// R2 design: no LDS staging of the A operand. Each thread owns ONE row and
// streams it global->register (float4, align-4 via memcpy; the 4 column-group
// waves of a block read the same lines ~together -> L1 hits). Weights are
// wave-uniform -> readfirstlane + scalar loads (K$/L2 path). LDS only for the
// 40-logit softmax exchange and the 32-wide head ping-pong.
// TM=64 rows/block, 256 threads, grid=1024 -> 4 blocks/CU, 16 waves/CU.

constexpr int OBS = 1129;
constexpr int TM  = 64;

__device__ __forceinline__ float4 ld4(const float* p) {
    float4 v;
    __builtin_memcpy(&v, p, 16);   // align-4 source; HW handles unaligned dwordx4
    return v;
}

__global__ __launch_bounds__(256, 4)
void qnet_fwd(const float* __restrict__ obs,
              const float* __restrict__ W_al,   const float* __restrict__ b_al,
              const float* __restrict__ W_self, const float* __restrict__ b_self,
              const float* __restrict__ W_oth,  const float* __restrict__ b_oth,
              const float* __restrict__ W_ao,   const float* __restrict__ b_ao,
              const float* __restrict__ W_emb,  const float* __restrict__ b_emb,
              const float* __restrict__ W_out,  const float* __restrict__ b_out,
              float* __restrict__ out)
{
    __shared__ float sLg[TM * 41];   // logits -> att_w -> head buffer A (stride 33)
    __shared__ float sH[TM * 33];    // head buffer B

    const int t   = threadIdx.x;
    const int rs  = t & 63;
    const int cg  = t >> 6;
    const int row = blockIdx.x * TM + rs;
    const float* __restrict__ orow = obs + (size_t)row * OBS;

    // ================= pass 1: logits = obs @ W_al + b_al =================
    const int j0 = __builtin_amdgcn_readfirstlane(cg * 10);

    float acc[10];
#pragma unroll
    for (int j = 0; j < 10; ++j) acc[j] = 0.f;

#pragma unroll 2
    for (int kc = 0; kc < 141; ++kc) {          // 141*8 = 1128
        const int k0 = kc * 8;
        float4 a0 = ld4(orow + k0);
        float4 a1 = ld4(orow + k0 + 4);
        float av[8] = {a0.x, a0.y, a0.z, a0.w, a1.x, a1.y, a1.z, a1.w};
        const float* wb = W_al + k0 * 40 + j0;  // wave-uniform -> scalar loads
#pragma unroll
        for (int k = 0; k < 8; ++k) {
#pragma unroll
            for (int j = 0; j < 10; ++j)
                acc[j] = fmaf(av[k], wb[k * 40 + j], acc[j]);
        }
    }
    {   // tail k = 1128
        float a = orow[1128];
        const float* wb = W_al + 1128 * 40 + j0;
#pragma unroll
        for (int j = 0; j < 10; ++j) acc[j] = fmaf(a, wb[j], acc[j]);
    }
#pragma unroll
    for (int j = 0; j < 10; ++j)
        sLg[rs * 41 + j0 + j] = acc[j] + b_al[j0 + j];
    __syncthreads();

    // softmax per row (threads 0..63, one row each; stride 41 = conflict-free)
    if (t < TM) {
        float* Lr = sLg + t * 41;
        float m = -3.4e38f;
        for (int j = 0; j < 40; ++j) m = fmaxf(m, Lr[j]);
        float s = 0.f;
        for (int j = 0; j < 40; ++j) s += __expf(Lr[j] - m);
        float inv = 1.0f / s;
        for (int j = 0; j < 40; ++j) Lr[j] = __expf(Lr[j] - m) * inv;
    }
    __syncthreads();

    // ================= pass 2: encodings + weighted sum =================
    const int e0 = __builtin_amdgcn_readfirstlane(cg * 8);
    float att[8];

    {   // self encoding (NO relu), weight att_w[0]
        float se[8];
#pragma unroll
        for (int j = 0; j < 8; ++j) se[j] = b_self[e0 + j];
#pragma unroll
        for (int kc = 0; kc < 9; ++kc) {        // 9*4 = 36
            float4 a = ld4(orow + kc * 4);
            float av[4] = {a.x, a.y, a.z, a.w};
#pragma unroll
            for (int k = 0; k < 4; ++k) {
                const float* w = W_self + (kc * 4 + k) * 32 + e0;
#pragma unroll
                for (int j = 0; j < 8; ++j) se[j] = fmaf(av[k], w[j], se[j]);
            }
        }
        {   // tail k = 36
            float a = orow[36];
            const float* w = W_self + 36 * 32 + e0;
#pragma unroll
            for (int j = 0; j < 8; ++j) se[j] = fmaf(a, w[j], se[j]);
        }
        float w0 = sLg[rs * 41];
#pragma unroll
        for (int j = 0; j < 8; ++j) att[j] = w0 * se[j];
    }

    // other agents: att_w[1+n] * relu(obs[37+28n : 65+28n] @ W_oth + b_oth)
    for (int n = 0; n < 39; ++n) {
        const float* op = orow + 37 + n * 28;
        float se[8];
#pragma unroll
        for (int j = 0; j < 8; ++j) se[j] = b_oth[e0 + j];
#pragma unroll
        for (int kc = 0; kc < 7; ++kc) {        // 7*4 = 28
            float4 a = ld4(op + kc * 4);
            float av[4] = {a.x, a.y, a.z, a.w};
#pragma unroll
            for (int k = 0; k < 4; ++k) {
                const float* w = W_oth + (kc * 4 + k) * 32 + e0;
#pragma unroll
                for (int j = 0; j < 8; ++j) se[j] = fmaf(av[k], w[j], se[j]);
            }
        }
        float wn = sLg[rs * 41 + 1 + n];
#pragma unroll
        for (int j = 0; j < 8; ++j) att[j] += wn * fmaxf(se[j], 0.f);
    }

    // ================= head: 3 small dense layers =================
    __syncthreads();                 // all att_w reads done
#pragma unroll
    for (int j = 0; j < 8; ++j) sLg[rs * 33 + e0 + j] = att[j];
    __syncthreads();

    // h1 = relu(att @ W_ao + b_ao) -> sH
    {
        float h[8];
#pragma unroll
        for (int j = 0; j < 8; ++j) h[j] = b_ao[e0 + j];
#pragma unroll
        for (int k = 0; k < 32; ++k) {
            float x = sLg[rs * 33 + k];          // stride 33, 1 row/lane: conflict-free
            const float* w = W_ao + k * 32 + e0;
#pragma unroll
            for (int j = 0; j < 8; ++j) h[j] = fmaf(x, w[j], h[j]);
        }
#pragma unroll
        for (int j = 0; j < 8; ++j) sH[rs * 33 + e0 + j] = fmaxf(h[j], 0.f);
    }
    __syncthreads();

    // h2 = relu(h1 @ W_emb + b_emb) -> sLg (att buffer dead)
    {
        float h[8];
#pragma unroll
        for (int j = 0; j < 8; ++j) h[j] = b_emb[e0 + j];
#pragma unroll
        for (int k = 0; k < 32; ++k) {
            float x = sH[rs * 33 + k];
            const float* w = W_emb + k * 32 + e0;
#pragma unroll
            for (int j = 0; j < 8; ++j) h[j] = fmaf(x, w[j], h[j]);
        }
#pragma unroll
        for (int j = 0; j < 8; ++j) sLg[rs * 33 + e0 + j] = fmaxf(h[j], 0.f);
    }
    __syncthreads();

    // out = h2 @ W_out + b_out   (21 cols: cg0,1 -> 8 each, cg2 -> 5, cg3 idle)
    if (cg < 3) {
        const int o0 = __builtin_amdgcn_readfirstlane(cg * 8);
        float o[8];
#pragma unroll
        for (int j = 0; j < 8; ++j) o[j] = (o0 + j < 21) ? b_out[o0 + j] : 0.f;
#pragma unroll
        for (int k = 0; k < 32; ++k) {
            float x = sLg[rs * 33 + k];
            const float* w = W_out + k * 21 + o0;
#pragma unroll
            for (int j = 0; j < 8; ++j)
                if (o0 + j < 21) o[j] = fmaf(x, w[j], o[j]);
        }
#pragma unroll
        for (int j = 0; j < 8; ++j)
            if (o0 + j < 21) out[(size_t)row * 21 + o0 + j] = o[j];
    }
}

extern "C" void kernel_launch(void* const* d_in, const int* in_sizes, int n_in,
                              void* d_out, int out_size, void* d_ws, size_t ws_size,
                              hipStream_t stream) {
    const float* obs    = (const float*)d_in[0];
    const float* W_al   = (const float*)d_in[1];
    const float* b_al   = (const float*)d_in[2];
    const float* W_self = (const float*)d_in[3];
    const float* b_self = (const float*)d_in[4];
    const float* W_oth  = (const float*)d_in[5];
    const float* b_oth  = (const float*)d_in[6];
    const float* W_ao   = (const float*)d_in[7];
    const float* b_ao   = (const float*)d_in[8];
    const float* W_emb  = (const float*)d_in[9];
    const float* b_emb  = (const float*)d_in[10];
    const float* W_out  = (const float*)d_in[11];
    const float* b_out  = (const float*)d_in[12];
    float* out = (float*)d_out;

    const int B = in_sizes[0] / OBS;        // 65536
    const int grid = B / TM;                // 1024
    qnet_fwd<<<grid, 256, 0, stream>>>(obs, W_al, b_al, W_self, b_self,
                                       W_oth, b_oth, W_ao, b_ao,
                                       W_emb, b_emb, W_out, b_out, out);
}

// Round 3
// 172.424 us; speedup vs baseline: 2.1511x; 1.9230x over previous
//
#include <hip/hip_runtime.h>

// QNet forward, MI355X — MFMA (split-bf16) version.
// B=65536 rows, obs=1129 (37 self + 39*28 others). All GEMM phases on
// v_mfma_f32_16x16x32_bf16 with x = hi(bf16) + lo(bf16) splitting:
//   a*b ~= ah*bh + ah*bl + al*bh   (3 MFMAs, ~2^-16 rel err, f32 accum)
// 1 wave per block, 16 obs-rows per wave, grid = B/16 = 4096.
// Weights pre-split & pre-swizzled into MFMA B-fragment order in d_ws by a
// prep kernel (runs first on the same stream every launch; deterministic).
//
// Fragment maps (gfx950 16x16x32 bf16, HW-verified C/D per guide §3):
//   A[row][k]: row = lane&15, k = 8*(lane>>4) + i   (i=0..7, bf16x8)
//   B[k][col]: col = lane&15, k = 8*(lane>>4) + i
//   C/D[row][col]: col = lane&15, row = 4*(lane>>4) + reg
//
// d_ws layout: 120 "units" of 128 bf16x8 (64 hi frags, 64 lo frags), 2 KB each:
//   W_al  (K=1129->1152, N=40->48): unit = c*3 + t, c in [0,36), t in [0,3)
//   W_self(K=37->64,  N=32): unit = 108 + c*2 + t, c in [0,2)
//   W_oth (K=28->32,  N=32): unit = 112 + t
//   W_ao  (K=32,      N=32): unit = 114 + t
//   W_emb (K=32,      N=32): unit = 116 + t
//   W_out (K=32, N=21->32): unit = 118 + t
// Total ws bytes = 120*2048 = 245760.

typedef __bf16 bf16x8 __attribute__((ext_vector_type(8)));
typedef float  f32x4  __attribute__((ext_vector_type(4)));

constexpr int OBS = 1129;

#define MFMA(a, b, c) __builtin_amdgcn_mfma_f32_16x16x32_bf16((a), (b), (c), 0, 0, 0)

__device__ __forceinline__ float4 ld4(const float* p) {
    float4 v;
    __builtin_memcpy(&v, p, 16);          // 4B-aligned source is fine
    return v;
}

__device__ __forceinline__ void split8(const float* a, bf16x8& h, bf16x8& l) {
#pragma unroll
    for (int i = 0; i < 8; ++i) {
        __bf16 hb = (__bf16)a[i];
        h[i] = hb;
        l[i] = (__bf16)(a[i] - (float)hb);
    }
}

__device__ __forceinline__ f32x4 mm3(bf16x8 ah, bf16x8 al, bf16x8 bh, bf16x8 bl, f32x4 c) {
    c = MFMA(ah, bh, c);
    c = MFMA(ah, bl, c);
    c = MFMA(al, bh, c);
    return c;
}

// ---------------- prep: split weights into fragment order ----------------
__global__ void prep_weights(const float* __restrict__ W_al,
                             const float* __restrict__ W_self,
                             const float* __restrict__ W_oth,
                             const float* __restrict__ W_ao,
                             const float* __restrict__ W_emb,
                             const float* __restrict__ W_out,
                             bf16x8* __restrict__ ws)
{
    const int u = blockIdx.x;     // 120 units
    const int l = threadIdx.x;    // 64 lanes
    const int s = l >> 4, col = l & 15;
    const float* W; int K, N, ld, c, t;
    if (u < 108)      { c = u / 3;         t = u % 3;         W = W_al;   K = 1129; N = 40; ld = 40; }
    else if (u < 112) { c = (u - 108) / 2; t = (u - 108) & 1; W = W_self; K = 37;   N = 32; ld = 32; }
    else if (u < 114) { c = 0;             t = u - 112;       W = W_oth;  K = 28;   N = 32; ld = 32; }
    else if (u < 116) { c = 0;             t = u - 114;       W = W_ao;   K = 32;   N = 32; ld = 32; }
    else if (u < 118) { c = 0;             t = u - 116;       W = W_emb;  K = 32;   N = 32; ld = 32; }
    else              { c = 0;             t = u - 118;       W = W_out;  K = 32;   N = 21; ld = 21; }
    const int j = t * 16 + col;
    bf16x8 h, lo;
#pragma unroll
    for (int i = 0; i < 8; ++i) {
        int k = c * 32 + s * 8 + i;
        float w = (k < K && j < N) ? W[k * ld + j] : 0.f;
        __bf16 hb = (__bf16)w;
        h[i]  = hb;
        lo[i] = (__bf16)(w - (float)hb);
    }
    ws[u * 128 + l]      = h;
    ws[u * 128 + 64 + l] = lo;
}

// ---------------- main kernel: 64 threads (1 wave), 16 rows ----------------
__global__ __launch_bounds__(64, 4)
void qnet_fwd(const float* __restrict__ obs,
              const float* __restrict__ b_al,
              const float* __restrict__ b_ao,
              const float* __restrict__ b_emb,
              const float* __restrict__ b_out,
              const bf16x8* __restrict__ wf,
              float* __restrict__ out)
{
    __shared__ float  sW[16 * 49];              // att weights [row][40], stride 49
    __shared__ __bf16 sHi[16 * 40], sLo[16 * 40];  // head exchange, stride 40

    const int l  = threadIdx.x;
    const int s  = l >> 4;                      // k-seg / C row-group
    const int cq = l & 15;                      // A row / C col
    const int b0 = blockIdx.x * 16;
    const float* __restrict__ orow = obs + (size_t)(b0 + cq) * OBS;

    const f32x4 zf = {0.f, 0.f, 0.f, 0.f};

    // ================= pass 1: logits = obs @ W_al =================
    f32x4 acc0 = zf, acc1 = zf, acc2 = zf;
    for (int c = 0; c < 35; ++c) {
        const int k0 = c * 32 + s * 8;
        float4 p = ld4(orow + k0), q = ld4(orow + k0 + 4);
        float av[8] = {p.x, p.y, p.z, p.w, q.x, q.y, q.z, q.w};
        bf16x8 ah, al; split8(av, ah, al);
        const bf16x8* bu = wf + (size_t)c * 3 * 128;
        acc0 = mm3(ah, al, bu[l],       bu[64 + l],  acc0);
        acc1 = mm3(ah, al, bu[128 + l], bu[192 + l], acc1);
        acc2 = mm3(ah, al, bu[256 + l], bu[320 + l], acc2);
    }
    {   // chunk 35: k = 1120..1151, valid <= 1128
        float av[8] = {0, 0, 0, 0, 0, 0, 0, 0};
        if (s == 0) {
            float4 p = ld4(orow + 1120), q = ld4(orow + 1124);
            av[0] = p.x; av[1] = p.y; av[2] = p.z; av[3] = p.w;
            av[4] = q.x; av[5] = q.y; av[6] = q.z; av[7] = q.w;
        } else if (s == 1) {
            av[0] = orow[1128];
        }
        bf16x8 ah, al; split8(av, ah, al);
        const bf16x8* bu = wf + (size_t)35 * 3 * 128;
        acc0 = mm3(ah, al, bu[l],       bu[64 + l],  acc0);
        acc1 = mm3(ah, al, bu[128 + l], bu[192 + l], acc1);
        acc2 = mm3(ah, al, bu[256 + l], bu[320 + l], acc2);
    }

    // ============ softmax over 40 cols (rows spread: row = 4s+j) ============
    {
        const float bal0 = b_al[cq];
        const float bal1 = b_al[16 + cq];
        const bool  v2   = (cq < 8);
        const float bal2 = v2 ? b_al[32 + cq] : 0.f;
#pragma unroll
        for (int j = 0; j < 4; ++j) {
            float v0 = acc0[j] + bal0, v1 = acc1[j] + bal1, vv = acc2[j] + bal2;
            float m = fmaxf(fmaxf(v0, v1), v2 ? vv : -3.4e38f);
#pragma unroll
            for (int d = 1; d < 16; d <<= 1) m = fmaxf(m, __shfl_xor(m, d));
            float e0 = __expf(v0 - m), e1 = __expf(v1 - m), e2 = v2 ? __expf(vv - m) : 0.f;
            float sm = e0 + e1 + e2;
#pragma unroll
            for (int d = 1; d < 16; d <<= 1) sm += __shfl_xor(sm, d);
            float inv = 1.f / sm;
            const int row = s * 4 + j;
            sW[row * 49 + cq]      = e0 * inv;
            sW[row * 49 + 16 + cq] = e1 * inv;
            if (v2) sW[row * 49 + 32 + cq] = e2 * inv;
        }
    }
    __syncthreads();

    // ================= pass 2: encodings, weighted sum =================
    f32x4 at0 = zf, at1 = zf;
    {   // self encoding (no relu), weight att_w[row][0]
        f32x4 e0 = zf, e1 = zf;
        {   // chunk 0: k = 0..31 (< 37, all valid)
            float4 p = ld4(orow + s * 8), q = ld4(orow + s * 8 + 4);
            float av[8] = {p.x, p.y, p.z, p.w, q.x, q.y, q.z, q.w};
            bf16x8 ah, al; split8(av, ah, al);
            const bf16x8* bu = wf + (size_t)108 * 128;
            e0 = mm3(ah, al, bu[l],       bu[64 + l],  e0);
            e1 = mm3(ah, al, bu[128 + l], bu[192 + l], e1);
        }
        {   // chunk 1: k = 32..63, valid 32..36
            float av[8] = {0, 0, 0, 0, 0, 0, 0, 0};
            if (s == 0) {
                float4 p = ld4(orow + 32);
                av[0] = p.x; av[1] = p.y; av[2] = p.z; av[3] = p.w;
                av[4] = orow[36];
            }
            bf16x8 ah, al; split8(av, ah, al);
            const bf16x8* bu = wf + (size_t)110 * 128;
            e0 = mm3(ah, al, bu[l],       bu[64 + l],  e0);
            e1 = mm3(ah, al, bu[128 + l], bu[192 + l], e1);
        }
#pragma unroll
        for (int j = 0; j < 4; ++j) {
            float w0 = sW[(s * 4 + j) * 49];
            at0[j] = w0 * e0[j];
            at1[j] = w0 * e1[j];
        }
    }

    // other agents: att_w[row][1+n] * relu(obs[37+28n ..] @ W_oth)
    for (int n = 0; n < 39; ++n) {
        const float* op = orow + 37 + n * 28;
        bf16x8 ah, al;
        if (s < 3) {
            float4 p = ld4(op + s * 8), q = ld4(op + s * 8 + 4);
            float av[8] = {p.x, p.y, p.z, p.w, q.x, q.y, q.z, q.w};
            split8(av, ah, al);
        } else {        // k = 24..31: valid 24..27
            float4 p = ld4(op + 24);
            float av[8] = {p.x, p.y, p.z, p.w, 0, 0, 0, 0};
            split8(av, ah, al);
        }
        const bf16x8* bu = wf + (size_t)112 * 128;
        f32x4 e0 = mm3(ah, al, bu[l],       bu[64 + l],  zf);
        f32x4 e1 = mm3(ah, al, bu[128 + l], bu[192 + l], zf);
#pragma unroll
        for (int j = 0; j < 4; ++j) {
            float wn = sW[(s * 4 + j) * 49 + 1 + n];
            at0[j] += wn * fmaxf(e0[j], 0.f);
            at1[j] += wn * fmaxf(e1[j], 0.f);
        }
    }

    // ================= head: 3 dense layers via LDS exchange =================
    f32x4 x0 = at0, x1 = at1;
#pragma unroll
    for (int L = 0; L < 3; ++L) {
        const int unit = 114 + L * 2;
        const float* bias = (L == 0) ? b_ao : (L == 1) ? b_emb : b_out;
        const int N = (L == 2) ? 21 : 32;
        // write C-layout -> LDS rows [16][32] bf16 hi/lo (stride 40)
#pragma unroll
        for (int j = 0; j < 4; ++j) {
            const int row = s * 4 + j;
            __bf16 h0 = (__bf16)x0[j];
            sHi[row * 40 + cq] = h0;
            sLo[row * 40 + cq] = (__bf16)(x0[j] - (float)h0);
            __bf16 h1 = (__bf16)x1[j];
            sHi[row * 40 + 16 + cq] = h1;
            sLo[row * 40 + 16 + cq] = (__bf16)(x1[j] - (float)h1);
        }
        __syncthreads();
        bf16x8 ah = *(const bf16x8*)&sHi[cq * 40 + s * 8];
        bf16x8 al = *(const bf16x8*)&sLo[cq * 40 + s * 8];
        __syncthreads();   // reads done before next layer overwrites
        const bf16x8* bu = wf + (size_t)unit * 128;
        f32x4 y0 = mm3(ah, al, bu[l],       bu[64 + l],  zf);
        f32x4 y1 = mm3(ah, al, bu[128 + l], bu[192 + l], zf);
        const float bc0 = bias[cq];
        const float bc1 = (16 + cq < N) ? bias[16 + cq] : 0.f;
#pragma unroll
        for (int j = 0; j < 4; ++j) {
            y0[j] += bc0;
            y1[j] += bc1;
            if (L < 2) { y0[j] = fmaxf(y0[j], 0.f); y1[j] = fmaxf(y1[j], 0.f); }
        }
        x0 = y0; x1 = y1;
    }

    // store out[row][col]: tile0 cols 0..15, tile1 cols 16..20
#pragma unroll
    for (int j = 0; j < 4; ++j) {
        const int row = b0 + s * 4 + j;
        out[(size_t)row * 21 + cq] = x0[j];
        if (cq < 5) out[(size_t)row * 21 + 16 + cq] = x1[j];
    }
}

extern "C" void kernel_launch(void* const* d_in, const int* in_sizes, int n_in,
                              void* d_out, int out_size, void* d_ws, size_t ws_size,
                              hipStream_t stream) {
    const float* obs    = (const float*)d_in[0];
    const float* W_al   = (const float*)d_in[1];
    const float* b_al   = (const float*)d_in[2];
    const float* W_self = (const float*)d_in[3];
    const float* W_oth  = (const float*)d_in[5];
    const float* W_ao   = (const float*)d_in[7];
    const float* b_ao   = (const float*)d_in[8];
    const float* W_emb  = (const float*)d_in[9];
    const float* b_emb  = (const float*)d_in[10];
    const float* W_out  = (const float*)d_in[11];
    const float* b_out  = (const float*)d_in[12];
    float* out = (float*)d_out;
    bf16x8* ws = (bf16x8*)d_ws;

    prep_weights<<<120, 64, 0, stream>>>(W_al, W_self, W_oth, W_ao, W_emb, W_out, ws);

    const int B = in_sizes[0] / OBS;        // 65536
    qnet_fwd<<<B / 16, 64, 0, stream>>>(obs, b_al, b_ao, b_emb, b_out,
                                        (const bf16x8*)ws, out);
}

// Round 4
// 169.887 us; speedup vs baseline: 2.1832x; 1.0149x over previous
//
#include <hip/hip_runtime.h>

// QNet forward, MI355X — MFMA split-bf16, software-pipelined (R4).
// B=65536 rows, obs=1129 (37 self + 39*28 others).
// 1 wave (64 thr) per block, 16 rows/wave, grid 4096, 16 blocks/CU target.
//
// R4 changes vs R3 (which was latency-bound: VALU 14%, MFMA 7%, hbm 18%):
//  - pass 1: depth-2 register prefetch of A (4 rotating bufs, unroll-4),
//    depth-1 prefetch of B fragments (2 bufs). No barriers, no LDS staging.
//  - pass 2: W_oth fragments hoisted out of the 39-agent loop; depth-2 A
//    prefetch (3 bufs, unroll-3); 2-term MFMA (drop A-lo) for other-agents
//    (error ~1e-3 at output, threshold 6.25e-3). Logits/self/head keep 3-term.
//
// Fragment maps (gfx950 16x16x32 bf16): A/B: row|col = lane&15, k = 8*(lane>>4)+i
//   C/D: col = lane&15, row = 4*(lane>>4) + reg
//
// d_ws: 120 units of 128 bf16x8 (64 hi + 64 lo frags), 2 KB each = 245760 B.
//   W_al: unit = c*3+t (c<36, t<3) | W_self: 108+c*2+t | W_oth: 112+t
//   W_ao: 114+t | W_emb: 116+t | W_out: 118+t

typedef __bf16 bf16x8 __attribute__((ext_vector_type(8)));
typedef float  f32x4  __attribute__((ext_vector_type(4)));

constexpr int OBS = 1129;

#define MFMA(a, b, c) __builtin_amdgcn_mfma_f32_16x16x32_bf16((a), (b), (c), 0, 0, 0)

__device__ __forceinline__ float4 ld4(const float* p) {
    float4 v;
    __builtin_memcpy(&v, p, 16);
    return v;
}

__device__ __forceinline__ void split8(const float* a, bf16x8& h, bf16x8& l) {
#pragma unroll
    for (int i = 0; i < 8; ++i) {
        __bf16 hb = (__bf16)a[i];
        h[i] = hb;
        l[i] = (__bf16)(a[i] - (float)hb);
    }
}

__device__ __forceinline__ f32x4 mm3(bf16x8 ah, bf16x8 al, bf16x8 bh, bf16x8 bl, f32x4 c) {
    c = MFMA(ah, bh, c);
    c = MFMA(ah, bl, c);
    c = MFMA(al, bh, c);
    return c;
}

// ---------------- prep: split weights into fragment order ----------------
__global__ void prep_weights(const float* __restrict__ W_al,
                             const float* __restrict__ W_self,
                             const float* __restrict__ W_oth,
                             const float* __restrict__ W_ao,
                             const float* __restrict__ W_emb,
                             const float* __restrict__ W_out,
                             bf16x8* __restrict__ ws)
{
    const int u = blockIdx.x;     // 120 units
    const int l = threadIdx.x;    // 64 lanes
    const int s = l >> 4, col = l & 15;
    const float* W; int K, N, ld, c, t;
    if (u < 108)      { c = u / 3;         t = u % 3;         W = W_al;   K = 1129; N = 40; ld = 40; }
    else if (u < 112) { c = (u - 108) / 2; t = (u - 108) & 1; W = W_self; K = 37;   N = 32; ld = 32; }
    else if (u < 114) { c = 0;             t = u - 112;       W = W_oth;  K = 28;   N = 32; ld = 32; }
    else if (u < 116) { c = 0;             t = u - 114;       W = W_ao;   K = 32;   N = 32; ld = 32; }
    else if (u < 118) { c = 0;             t = u - 116;       W = W_emb;  K = 32;   N = 32; ld = 32; }
    else              { c = 0;             t = u - 118;       W = W_out;  K = 32;   N = 21; ld = 21; }
    const int j = t * 16 + col;
    bf16x8 h, lo;
#pragma unroll
    for (int i = 0; i < 8; ++i) {
        int k = c * 32 + s * 8 + i;
        float w = (k < K && j < N) ? W[k * ld + j] : 0.f;
        __bf16 hb = (__bf16)w;
        h[i]  = hb;
        lo[i] = (__bf16)(w - (float)hb);
    }
    ws[u * 128 + l]      = h;
    ws[u * 128 + 64 + l] = lo;
}

// pass-1 A loader: chunk c covers k = 32c .. 32c+31; chunk 35 masked tail.
__device__ __forceinline__ void loadA1(const float* __restrict__ orow, int s, int c, float* av) {
    if (c < 35) {
        const int k0 = c * 32 + s * 8;
        float4 p = ld4(orow + k0), q = ld4(orow + k0 + 4);
        av[0] = p.x; av[1] = p.y; av[2] = p.z; av[3] = p.w;
        av[4] = q.x; av[5] = q.y; av[6] = q.z; av[7] = q.w;
    } else {
#pragma unroll
        for (int i = 0; i < 8; ++i) av[i] = 0.f;
        if (s == 0) {
            float4 p = ld4(orow + 1120), q = ld4(orow + 1124);
            av[0] = p.x; av[1] = p.y; av[2] = p.z; av[3] = p.w;
            av[4] = q.x; av[5] = q.y; av[6] = q.z; av[7] = q.w;
        } else if (s == 1) {
            av[0] = orow[1128];
        }
    }
}

__device__ __forceinline__ void loadB1(const bf16x8* __restrict__ wf, int l, int c, bf16x8* B) {
    const bf16x8* bu = wf + (size_t)c * 3 * 128;
    B[0] = bu[l];       B[1] = bu[64 + l];
    B[2] = bu[128 + l]; B[3] = bu[192 + l];
    B[4] = bu[256 + l]; B[5] = bu[320 + l];
}

// pass-2 A loader: agent n, k = 0..27 (+4 zero pad on s==3)
__device__ __forceinline__ void loadA2(const float* __restrict__ orow, int s, int n, float* av) {
    const float* op = orow + 37 + n * 28;
    if (s < 3) {
        float4 p = ld4(op + s * 8), q = ld4(op + s * 8 + 4);
        av[0] = p.x; av[1] = p.y; av[2] = p.z; av[3] = p.w;
        av[4] = q.x; av[5] = q.y; av[6] = q.z; av[7] = q.w;
    } else {
        float4 p = ld4(op + 24);
        av[0] = p.x; av[1] = p.y; av[2] = p.z; av[3] = p.w;
        av[4] = 0.f; av[5] = 0.f; av[6] = 0.f; av[7] = 0.f;
    }
}

// ---------------- main kernel: 64 threads (1 wave), 16 rows ----------------
__global__ __launch_bounds__(64, 4)
void qnet_fwd(const float* __restrict__ obs,
              const float* __restrict__ b_al,
              const float* __restrict__ b_ao,
              const float* __restrict__ b_emb,
              const float* __restrict__ b_out,
              const bf16x8* __restrict__ wf,
              float* __restrict__ out)
{
    __shared__ float  sW[16 * 49];                 // att weights [row][40], stride 49
    __shared__ __bf16 sHi[16 * 40], sLo[16 * 40];  // head exchange, stride 40

    const int l  = threadIdx.x;
    const int s  = l >> 4;
    const int cq = l & 15;
    const int b0 = blockIdx.x * 16;
    const float* __restrict__ orow = obs + (size_t)(b0 + cq) * OBS;

    const f32x4 zf = {0.f, 0.f, 0.f, 0.f};

    // ================= pass 1: logits = obs @ W_al (pipelined) =================
    f32x4 acc0 = zf, acc1 = zf, acc2 = zf;

    float  a0[8], a1[8], a2[8], a3[8];
    bf16x8 B0[6], B1[6];

    loadA1(orow, s, 0, a0);
    loadB1(wf, l, 0, B0);
    loadA1(orow, s, 1, a1);

#define COMPUTE1(AV, BB)                                             \
    do {                                                             \
        bf16x8 ah, al; split8((AV), ah, al);                         \
        acc0 = mm3(ah, al, (BB)[0], (BB)[1], acc0);                  \
        acc1 = mm3(ah, al, (BB)[2], (BB)[3], acc1);                  \
        acc2 = mm3(ah, al, (BB)[4], (BB)[5], acc2);                  \
    } while (0)

    for (int it = 0; it < 9; ++it) {
        const int c = it * 4;
        loadB1(wf, l, c + 1, B1);
        if (c + 2 < 36) loadA1(orow, s, c + 2, a2);
        COMPUTE1(a0, B0);
        loadB1(wf, l, c + 2 < 36 ? c + 2 : 35, B0);
        if (c + 3 < 36) loadA1(orow, s, c + 3, a3);
        COMPUTE1(a1, B1);
        if (c + 3 < 36) loadB1(wf, l, c + 3, B1);
        if (c + 4 < 36) loadA1(orow, s, c + 4, a0);
        if (c + 2 < 36) COMPUTE1(a2, B0);
        if (c + 4 < 36) loadB1(wf, l, c + 4, B0);
        if (c + 5 < 36) loadA1(orow, s, c + 5, a1);
        if (c + 3 < 36) COMPUTE1(a3, B1);
    }

    // ============ softmax over 40 cols (C rows spread: row = 4s+j) ============
    {
        const float bal0 = b_al[cq];
        const float bal1 = b_al[16 + cq];
        const bool  v2   = (cq < 8);
        const float bal2 = v2 ? b_al[32 + cq] : 0.f;
#pragma unroll
        for (int j = 0; j < 4; ++j) {
            float v0 = acc0[j] + bal0, v1 = acc1[j] + bal1, vv = acc2[j] + bal2;
            float m = fmaxf(fmaxf(v0, v1), v2 ? vv : -3.4e38f);
#pragma unroll
            for (int d = 1; d < 16; d <<= 1) m = fmaxf(m, __shfl_xor(m, d));
            float e0 = __expf(v0 - m), e1 = __expf(v1 - m), e2 = v2 ? __expf(vv - m) : 0.f;
            float sm = e0 + e1 + e2;
#pragma unroll
            for (int d = 1; d < 16; d <<= 1) sm += __shfl_xor(sm, d);
            float inv = 1.f / sm;
            const int row = s * 4 + j;
            sW[row * 49 + cq]      = e0 * inv;
            sW[row * 49 + 16 + cq] = e1 * inv;
            if (v2) sW[row * 49 + 32 + cq] = e2 * inv;
        }
    }
    __syncthreads();

    // ================= pass 2: encodings, weighted sum =================
    f32x4 at0 = zf, at1 = zf;

    {   // self encoding (no relu), 3-term, weight att_w[row][0]
        f32x4 e0 = zf, e1 = zf;
        {
            float4 p = ld4(orow + s * 8), q = ld4(orow + s * 8 + 4);
            float av[8] = {p.x, p.y, p.z, p.w, q.x, q.y, q.z, q.w};
            bf16x8 ah, al; split8(av, ah, al);
            const bf16x8* bu = wf + (size_t)108 * 128;
            e0 = mm3(ah, al, bu[l],       bu[64 + l],  e0);
            e1 = mm3(ah, al, bu[128 + l], bu[192 + l], e1);
        }
        {
            float av[8] = {0, 0, 0, 0, 0, 0, 0, 0};
            if (s == 0) {
                float4 p = ld4(orow + 32);
                av[0] = p.x; av[1] = p.y; av[2] = p.z; av[3] = p.w;
                av[4] = orow[36];
            }
            bf16x8 ah, al; split8(av, ah, al);
            const bf16x8* bu = wf + (size_t)110 * 128;
            e0 = mm3(ah, al, bu[l],       bu[64 + l],  e0);
            e1 = mm3(ah, al, bu[128 + l], bu[192 + l], e1);
        }
#pragma unroll
        for (int j = 0; j < 4; ++j) {
            float w0 = sW[(s * 4 + j) * 49];
            at0[j] = w0 * e0[j];
            at1[j] = w0 * e1[j];
        }
    }

    // other agents: 2-term (A hi only), W_oth frags hoisted, depth-2 A prefetch
    {
        const bf16x8* bo = wf + (size_t)112 * 128;
        const bf16x8 Boh0 = bo[l],       Bol0 = bo[64 + l];
        const bf16x8 Boh1 = bo[128 + l], Bol1 = bo[192 + l];

        float p0[8], p1[8], p2[8];
        loadA2(orow, s, 0, p0);
        loadA2(orow, s, 1, p1);

#define COMPUTE2(N, AV)                                               \
    do {                                                              \
        bf16x8 ah;                                                    \
        _Pragma("unroll")                                             \
        for (int i = 0; i < 8; ++i) ah[i] = (__bf16)(AV)[i];          \
        f32x4 e0 = MFMA(ah, Boh0, zf); e0 = MFMA(ah, Bol0, e0);       \
        f32x4 e1 = MFMA(ah, Boh1, zf); e1 = MFMA(ah, Bol1, e1);       \
        _Pragma("unroll")                                             \
        for (int j = 0; j < 4; ++j) {                                 \
            float wn = sW[(s * 4 + j) * 49 + 1 + (N)];                \
            at0[j] += wn * fmaxf(e0[j], 0.f);                         \
            at1[j] += wn * fmaxf(e1[j], 0.f);                         \
        }                                                             \
    } while (0)

        for (int it = 0; it < 13; ++it) {
            const int n = it * 3;
            if (n + 2 < 39) loadA2(orow, s, n + 2, p2);
            COMPUTE2(n, p0);
            if (n + 3 < 39) loadA2(orow, s, n + 3, p0);
            COMPUTE2(n + 1, p1);
            if (n + 4 < 39) loadA2(orow, s, n + 4, p1);
            if (n + 2 < 39) COMPUTE2(n + 2, p2);
        }
    }

    // ================= head: 3 dense layers via LDS exchange =================
    f32x4 x0 = at0, x1 = at1;
#pragma unroll
    for (int L = 0; L < 3; ++L) {
        const int unit = 114 + L * 2;
        const float* bias = (L == 0) ? b_ao : (L == 1) ? b_emb : b_out;
        const int N = (L == 2) ? 21 : 32;
#pragma unroll
        for (int j = 0; j < 4; ++j) {
            const int row = s * 4 + j;
            __bf16 h0 = (__bf16)x0[j];
            sHi[row * 40 + cq] = h0;
            sLo[row * 40 + cq] = (__bf16)(x0[j] - (float)h0);
            __bf16 h1 = (__bf16)x1[j];
            sHi[row * 40 + 16 + cq] = h1;
            sLo[row * 40 + 16 + cq] = (__bf16)(x1[j] - (float)h1);
        }
        __syncthreads();
        bf16x8 ah = *(const bf16x8*)&sHi[cq * 40 + s * 8];
        bf16x8 al = *(const bf16x8*)&sLo[cq * 40 + s * 8];
        __syncthreads();
        const bf16x8* bu = wf + (size_t)unit * 128;
        f32x4 y0 = mm3(ah, al, bu[l],       bu[64 + l],  zf);
        f32x4 y1 = mm3(ah, al, bu[128 + l], bu[192 + l], zf);
        const float bc0 = bias[cq];
        const float bc1 = (16 + cq < N) ? bias[16 + cq] : 0.f;
#pragma unroll
        for (int j = 0; j < 4; ++j) {
            y0[j] += bc0;
            y1[j] += bc1;
            if (L < 2) { y0[j] = fmaxf(y0[j], 0.f); y1[j] = fmaxf(y1[j], 0.f); }
        }
        x0 = y0; x1 = y1;
    }

    // store out[row][col]: tile0 cols 0..15, tile1 cols 16..20
#pragma unroll
    for (int j = 0; j < 4; ++j) {
        const int row = b0 + s * 4 + j;
        out[(size_t)row * 21 + cq] = x0[j];
        if (cq < 5) out[(size_t)row * 21 + 16 + cq] = x1[j];
    }
}

extern "C" void kernel_launch(void* const* d_in, const int* in_sizes, int n_in,
                              void* d_out, int out_size, void* d_ws, size_t ws_size,
                              hipStream_t stream) {
    const float* obs    = (const float*)d_in[0];
    const float* W_al   = (const float*)d_in[1];
    const float* b_al   = (const float*)d_in[2];
    const float* W_self = (const float*)d_in[3];
    const float* W_oth  = (const float*)d_in[5];
    const float* W_ao   = (const float*)d_in[7];
    const float* b_ao   = (const float*)d_in[8];
    const float* W_emb  = (const float*)d_in[9];
    const float* b_emb  = (const float*)d_in[10];
    const float* W_out  = (const float*)d_in[11];
    const float* b_out  = (const float*)d_in[12];
    float* out = (float*)d_out;
    bf16x8* ws = (bf16x8*)d_ws;

    prep_weights<<<120, 64, 0, stream>>>(W_al, W_self, W_oth, W_ao, W_emb, W_out, ws);

    const int B = in_sizes[0] / OBS;        // 65536
    qnet_fwd<<<B / 16, 64, 0, stream>>>(obs, b_al, b_ao, b_emb, b_out,
                                        (const bf16x8*)ws, out);
}

// Round 5
// 159.504 us; speedup vs baseline: 2.3253x; 1.0651x over previous
//
#include <hip/hip_runtime.h>

// QNet forward, MI355X — R5: multi-wave blocks + global_load_lds B-staging.
// B=65536 rows, obs=1129 (37 self + 39*28 others).
// 256-thr blocks (4 waves), 64 rows/block, grid 1024 -> 4 blocks/CU, 16 waves/CU.
//
// R4 post-mortem: one load in flight per wave (~650cy each, ~520 loads/block).
// R5: pass-1 W_al fragments staged into double-buffered LDS by global_load_lds
// (no VGPR write -> no wait until the per-chunk barrier => structural MLP),
// shared by 4 waves (B traffic /4). A stays in regs, issued early, consumed
// next chunk (barrier vmcnt drain = arrival). Pass 2: 4-agent load batches.
// Softmax + head are intra-wave only -> barrier-free, waves drift apart.
//
// Fragment maps (gfx950 16x16x32 bf16): A/B: row|col = lane&15, k = 8*(lane>>4)+i
//   C/D: col = lane&15, row = 4*(lane>>4) + reg
// Split-bf16: a*b ~= ah*bh + ah*bl + al*bh (3 MFMA; pass-2 others: 2-term).
//
// d_ws: 120 units of 128 bf16x8 (64 hi + 64 lo frags), 2 KB each = 245760 B.
//   W_al: unit = c*3+t (c<36, t<3) | W_self: 108+c*2+t | W_oth: 112+t
//   W_ao: 114+t | W_emb: 116+t | W_out: 118+t

typedef __bf16 bf16x8 __attribute__((ext_vector_type(8)));
typedef float  f32x4  __attribute__((ext_vector_type(4)));

constexpr int OBS = 1129;

#define MFMA(a, b, c) __builtin_amdgcn_mfma_f32_16x16x32_bf16((a), (b), (c), 0, 0, 0)

__device__ __forceinline__ float4 ld4(const float* p) {
    float4 v;
    __builtin_memcpy(&v, p, 16);
    return v;
}

__device__ __forceinline__ void split8(const float* a, bf16x8& h, bf16x8& l) {
#pragma unroll
    for (int i = 0; i < 8; ++i) {
        __bf16 hb = (__bf16)a[i];
        h[i] = hb;
        l[i] = (__bf16)(a[i] - (float)hb);
    }
}

__device__ __forceinline__ f32x4 mm3(bf16x8 ah, bf16x8 al, bf16x8 bh, bf16x8 bl, f32x4 c) {
    c = MFMA(ah, bh, c);
    c = MFMA(ah, bl, c);
    c = MFMA(al, bh, c);
    return c;
}

// async global->LDS, 16 B per lane; dst is wave-uniform base (HW adds lane*16)
__device__ __forceinline__ void glds16(const void* g, void* l) {
    __builtin_amdgcn_global_load_lds((const __attribute__((address_space(1))) void*)g,
                                     (__attribute__((address_space(3))) void*)l, 16, 0, 0);
}

// ---------------- prep: split weights into fragment order ----------------
__global__ void prep_weights(const float* __restrict__ W_al,
                             const float* __restrict__ W_self,
                             const float* __restrict__ W_oth,
                             const float* __restrict__ W_ao,
                             const float* __restrict__ W_emb,
                             const float* __restrict__ W_out,
                             bf16x8* __restrict__ ws)
{
    const int u = blockIdx.x;     // 120 units
    const int l = threadIdx.x;    // 64 lanes
    const int s = l >> 4, col = l & 15;
    const float* W; int K, N, ld, c, t;
    if (u < 108)      { c = u / 3;         t = u % 3;         W = W_al;   K = 1129; N = 40; ld = 40; }
    else if (u < 112) { c = (u - 108) / 2; t = (u - 108) & 1; W = W_self; K = 37;   N = 32; ld = 32; }
    else if (u < 114) { c = 0;             t = u - 112;       W = W_oth;  K = 28;   N = 32; ld = 32; }
    else if (u < 116) { c = 0;             t = u - 114;       W = W_ao;   K = 32;   N = 32; ld = 32; }
    else if (u < 118) { c = 0;             t = u - 116;       W = W_emb;  K = 32;   N = 32; ld = 32; }
    else              { c = 0;             t = u - 118;       W = W_out;  K = 32;   N = 21; ld = 21; }
    const int j = t * 16 + col;
    bf16x8 h, lo;
#pragma unroll
    for (int i = 0; i < 8; ++i) {
        int k = c * 32 + s * 8 + i;
        float w = (k < K && j < N) ? W[k * ld + j] : 0.f;
        __bf16 hb = (__bf16)w;
        h[i]  = hb;
        lo[i] = (__bf16)(w - (float)hb);
    }
    ws[u * 128 + l]      = h;
    ws[u * 128 + 64 + l] = lo;
}

// pass-1 A loader: chunk c covers k = 32c..32c+31; chunk 35 masked tail.
__device__ __forceinline__ void loadA1(const float* __restrict__ orow, int s, int c, float* av) {
    if (c < 35) {
        const int k0 = c * 32 + s * 8;
        float4 p = ld4(orow + k0), q = ld4(orow + k0 + 4);
        av[0] = p.x; av[1] = p.y; av[2] = p.z; av[3] = p.w;
        av[4] = q.x; av[5] = q.y; av[6] = q.z; av[7] = q.w;
    } else {
#pragma unroll
        for (int i = 0; i < 8; ++i) av[i] = 0.f;
        if (s == 0) {
            float4 p = ld4(orow + 1120), q = ld4(orow + 1124);
            av[0] = p.x; av[1] = p.y; av[2] = p.z; av[3] = p.w;
            av[4] = q.x; av[5] = q.y; av[6] = q.z; av[7] = q.w;
        } else if (s == 1) {
            av[0] = orow[1128];
        }
    }
}

// pass-2 A loader: agent n, k = 0..27 (+4 zero pad on s==3)
__device__ __forceinline__ void loadA2(const float* __restrict__ orow, int s, int n, float* av) {
    const float* op = orow + 37 + n * 28;
    if (s < 3) {
        float4 p = ld4(op + s * 8), q = ld4(op + s * 8 + 4);
        av[0] = p.x; av[1] = p.y; av[2] = p.z; av[3] = p.w;
        av[4] = q.x; av[5] = q.y; av[6] = q.z; av[7] = q.w;
    } else {
        float4 p = ld4(op + 24);
        av[0] = p.x; av[1] = p.y; av[2] = p.z; av[3] = p.w;
        av[4] = 0.f; av[5] = 0.f; av[6] = 0.f; av[7] = 0.f;
    }
}

// ---------------- main kernel: 256 threads (4 waves), 64 rows ----------------
__global__ __launch_bounds__(256, 4)
void qnet_fwd(const float* __restrict__ obs,
              const float* __restrict__ b_al,
              const float* __restrict__ b_ao,
              const float* __restrict__ b_emb,
              const float* __restrict__ b_out,
              const bf16x8* __restrict__ wf,
              float* __restrict__ out)
{
    __shared__ __align__(16) char  sB[2][6144];     // B-frag double buffer (3 units)
    __shared__ float  sW[4 * 784];                  // per-wave att weights [16][49]
    __shared__ __bf16 sHi[4 * 640], sLo[4 * 640];   // per-wave head exchange [16][40]

    const int t    = threadIdx.x;
    const int lane = t & 63;
    const int wv   = t >> 6;
    const int s    = lane >> 4;
    const int cq   = lane & 15;
    const int row0 = blockIdx.x * 64 + wv * 16;
    const float* __restrict__ orow = obs + (size_t)(row0 + cq) * OBS;
    const char* __restrict__ wfb = (const char*)wf;
    float* __restrict__ sWw = sW + wv * 784;

    const f32x4 zf = {0.f, 0.f, 0.f, 0.f};

    // ================= pass 1: logits = obs @ W_al =================
    f32x4 acc0 = zf, acc1 = zf, acc2 = zf;
    float Ar[8];

    // stage chunk c into dst: 6x 1KB pieces, distributed across waves
#define STAGE_B(DST, C)                                                          \
    do {                                                                         \
        const char* _src = wfb + (size_t)(C) * 6144;                             \
        glds16(_src + wv * 1024 + lane * 16, (DST) + wv * 1024);                 \
        if (wv < 2)                                                              \
            glds16(_src + (4 + wv) * 1024 + lane * 16, (DST) + (4 + wv) * 1024); \
    } while (0)

#define COMPUTE_B(SRC, AH, AL)                                                   \
    do {                                                                         \
        const char* _bp = (SRC);                                                 \
        bf16x8 b0h = *(const bf16x8*)(_bp + lane * 16);                          \
        bf16x8 b0l = *(const bf16x8*)(_bp + 1024 + lane * 16);                   \
        bf16x8 b1h = *(const bf16x8*)(_bp + 2048 + lane * 16);                   \
        bf16x8 b1l = *(const bf16x8*)(_bp + 3072 + lane * 16);                   \
        bf16x8 b2h = *(const bf16x8*)(_bp + 4096 + lane * 16);                   \
        bf16x8 b2l = *(const bf16x8*)(_bp + 5120 + lane * 16);                   \
        acc0 = mm3((AH), (AL), b0h, b0l, acc0);                                  \
        acc1 = mm3((AH), (AL), b1h, b1l, acc1);                                  \
        acc2 = mm3((AH), (AL), b2h, b2l, acc2);                                  \
    } while (0)

    STAGE_B(sB[0], 0);
    loadA1(orow, s, 0, Ar);
    __syncthreads();                          // drains glds(0) + A(0)

    for (int c = 0; c < 35; ++c) {
        STAGE_B(sB[(c + 1) & 1], c + 1);      // wait-free issue (no VGPR dest)
        bf16x8 ah, al;
        split8(Ar, ah, al);                   // consume A(c)
        loadA1(orow, s, c + 1, Ar);           // issue A(c+1), used next iter
        COMPUTE_B(sB[c & 1], ah, al);
        __syncthreads();                      // drain: B(c+1) in LDS, A(c+1) in regs
    }
    {   // peeled last chunk (35): no staging, no barrier after
        bf16x8 ah, al;
        split8(Ar, ah, al);
        COMPUTE_B(sB[1], ah, al);
    }

    // ===== softmax over 40 cols (intra-wave; C rows spread: row = 4s+j) =====
    {
        const float bal0 = b_al[cq];
        const float bal1 = b_al[16 + cq];
        const bool  v2   = (cq < 8);
        const float bal2 = v2 ? b_al[32 + cq] : 0.f;
#pragma unroll
        for (int j = 0; j < 4; ++j) {
            float v0 = acc0[j] + bal0, v1 = acc1[j] + bal1, vv = acc2[j] + bal2;
            float m = fmaxf(fmaxf(v0, v1), v2 ? vv : -3.4e38f);
#pragma unroll
            for (int d = 1; d < 16; d <<= 1) m = fmaxf(m, __shfl_xor(m, d));
            float e0 = __expf(v0 - m), e1 = __expf(v1 - m), e2 = v2 ? __expf(vv - m) : 0.f;
            float sm = e0 + e1 + e2;
#pragma unroll
            for (int d = 1; d < 16; d <<= 1) sm += __shfl_xor(sm, d);
            float inv = 1.f / sm;
            const int row = s * 4 + j;
            sWw[row * 49 + cq]      = e0 * inv;
            sWw[row * 49 + 16 + cq] = e1 * inv;
            if (v2) sWw[row * 49 + 32 + cq] = e2 * inv;
        }
    }
    // no barrier: sWw is wave-private, LDS ops wave-ordered

    // ================= pass 2: encodings, weighted sum =================
    f32x4 at0 = zf, at1 = zf;

    {   // self encoding (no relu), 3-term, weight att_w[row][0]
        f32x4 e0 = zf, e1 = zf;
        {
            float4 p = ld4(orow + s * 8), q = ld4(orow + s * 8 + 4);
            float av[8] = {p.x, p.y, p.z, p.w, q.x, q.y, q.z, q.w};
            bf16x8 ah, al; split8(av, ah, al);
            const bf16x8* bu = wf + (size_t)108 * 128;
            e0 = mm3(ah, al, bu[lane],       bu[64 + lane],  e0);
            e1 = mm3(ah, al, bu[128 + lane], bu[192 + lane], e1);
        }
        {
            float av[8] = {0, 0, 0, 0, 0, 0, 0, 0};
            if (s == 0) {
                float4 p = ld4(orow + 32);
                av[0] = p.x; av[1] = p.y; av[2] = p.z; av[3] = p.w;
                av[4] = orow[36];
            }
            bf16x8 ah, al; split8(av, ah, al);
            const bf16x8* bu = wf + (size_t)110 * 128;
            e0 = mm3(ah, al, bu[lane],       bu[64 + lane],  e0);
            e1 = mm3(ah, al, bu[128 + lane], bu[192 + lane], e1);
        }
#pragma unroll
        for (int j = 0; j < 4; ++j) {
            float w0 = sWw[(s * 4 + j) * 49];
            at0[j] = w0 * e0[j];
            at1[j] = w0 * e1[j];
        }
    }

    // other agents: 2-term (A hi only), W_oth hoisted, 4-agent load batches
    {
        const bf16x8* bo = wf + (size_t)112 * 128;
        const bf16x8 Boh0 = bo[lane],       Bol0 = bo[64 + lane];
        const bf16x8 Boh1 = bo[128 + lane], Bol1 = bo[192 + lane];

#define PROC_AGENT(N, AV)                                             \
    do {                                                              \
        bf16x8 ah;                                                    \
        _Pragma("unroll")                                             \
        for (int i = 0; i < 8; ++i) ah[i] = (__bf16)(AV)[i];          \
        f32x4 e0 = MFMA(ah, Boh0, zf); e0 = MFMA(ah, Bol0, e0);       \
        f32x4 e1 = MFMA(ah, Boh1, zf); e1 = MFMA(ah, Bol1, e1);       \
        _Pragma("unroll")                                             \
        for (int j = 0; j < 4; ++j) {                                 \
            float wn = sWw[(s * 4 + j) * 49 + 1 + (N)];               \
            at0[j] += wn * fmaxf(e0[j], 0.f);                         \
            at1[j] += wn * fmaxf(e1[j], 0.f);                         \
        }                                                             \
    } while (0)

        for (int g = 0; g < 9; ++g) {         // 9 groups of 4 agents
            const int n = g * 4;
            float q0[8], q1[8], q2[8], q3[8];
            loadA2(orow, s, n + 0, q0);       // 8 independent loads in flight
            loadA2(orow, s, n + 1, q1);
            loadA2(orow, s, n + 2, q2);
            loadA2(orow, s, n + 3, q3);
            PROC_AGENT(n + 0, q0);
            PROC_AGENT(n + 1, q1);
            PROC_AGENT(n + 2, q2);
            PROC_AGENT(n + 3, q3);
        }
        {   // tail: agents 36..38
            float q0[8], q1[8], q2[8];
            loadA2(orow, s, 36, q0);
            loadA2(orow, s, 37, q1);
            loadA2(orow, s, 38, q2);
            PROC_AGENT(36, q0);
            PROC_AGENT(37, q1);
            PROC_AGENT(38, q2);
        }
    }

    // ============ head: 3 dense layers, intra-wave LDS exchange ============
    __bf16* __restrict__ hiw = sHi + wv * 640;
    __bf16* __restrict__ low = sLo + wv * 640;
    f32x4 x0 = at0, x1 = at1;
#pragma unroll
    for (int L = 0; L < 3; ++L) {
        const int unit = 114 + L * 2;
        const float* bias = (L == 0) ? b_ao : (L == 1) ? b_emb : b_out;
        const int N = (L == 2) ? 21 : 32;
#pragma unroll
        for (int j = 0; j < 4; ++j) {
            const int row = s * 4 + j;
            __bf16 h0 = (__bf16)x0[j];
            hiw[row * 40 + cq] = h0;
            low[row * 40 + cq] = (__bf16)(x0[j] - (float)h0);
            __bf16 h1 = (__bf16)x1[j];
            hiw[row * 40 + 16 + cq] = h1;
            low[row * 40 + 16 + cq] = (__bf16)(x1[j] - (float)h1);
        }
        // wave-synchronous: ds_write -> lgkmcnt -> ds_read, same wave only
        bf16x8 ah = *(const bf16x8*)&hiw[cq * 40 + s * 8];
        bf16x8 al = *(const bf16x8*)&low[cq * 40 + s * 8];
        const bf16x8* bu = wf + (size_t)unit * 128;
        f32x4 y0 = mm3(ah, al, bu[lane],       bu[64 + lane],  zf);
        f32x4 y1 = mm3(ah, al, bu[128 + lane], bu[192 + lane], zf);
        const float bc0 = bias[cq];
        const float bc1 = (16 + cq < N) ? bias[16 + cq] : 0.f;
#pragma unroll
        for (int j = 0; j < 4; ++j) {
            y0[j] += bc0;
            y1[j] += bc1;
            if (L < 2) { y0[j] = fmaxf(y0[j], 0.f); y1[j] = fmaxf(y1[j], 0.f); }
        }
        x0 = y0; x1 = y1;
    }

    // store out[row][col]: tile0 cols 0..15, tile1 cols 16..20
#pragma unroll
    for (int j = 0; j < 4; ++j) {
        const int row = row0 + s * 4 + j;
        out[(size_t)row * 21 + cq] = x0[j];
        if (cq < 5) out[(size_t)row * 21 + 16 + cq] = x1[j];
    }
}

extern "C" void kernel_launch(void* const* d_in, const int* in_sizes, int n_in,
                              void* d_out, int out_size, void* d_ws, size_t ws_size,
                              hipStream_t stream) {
    const float* obs    = (const float*)d_in[0];
    const float* W_al   = (const float*)d_in[1];
    const float* b_al   = (const float*)d_in[2];
    const float* W_self = (const float*)d_in[3];
    const float* W_oth  = (const float*)d_in[5];
    const float* W_ao   = (const float*)d_in[7];
    const float* b_ao   = (const float*)d_in[8];
    const float* W_emb  = (const float*)d_in[9];
    const float* b_emb  = (const float*)d_in[10];
    const float* W_out  = (const float*)d_in[11];
    const float* b_out  = (const float*)d_in[12];
    float* out = (float*)d_out;
    bf16x8* ws = (bf16x8*)d_ws;

    prep_weights<<<120, 64, 0, stream>>>(W_al, W_self, W_oth, W_ao, W_emb, W_out, ws);

    const int B = in_sizes[0] / OBS;        // 65536
    qnet_fwd<<<B / 64, 256, 0, stream>>>(obs, b_al, b_ao, b_emb, b_out,
                                         (const bf16x8*)ws, out);
}